// Round 1
// baseline (510.099 us; speedup 1.0000x reference)
//
#include <hip/hip_runtime.h>

namespace {

constexpr int T   = 2048;
constexpr int B   = 8192;
constexpr int C   = 32;        // steps per barrier round
constexpr int NCH = T / C;     // 64 rounds
constexpr int RD  = 32;        // x prefetch ring depth (coverage >= HBM latency even at ~60cyc/step)

// Packed 2xf32 — maps to VOP3P v_pk_mul_f32 / v_pk_add_f32 on gfx950 (full-rate,
// per-component IEEE identical to scalar v_mul/v_add, so bit-exactness holds).
typedef float v2f __attribute__((ext_vector_type(2)));

// LDS-only barrier: waits lgkmcnt(0), leaves vmcnt alone so global prefetch
// stays in flight across rounds (R4-proven).
__device__ __forceinline__ void barrier_nodrain() {
    asm volatile("s_waitcnt lgkmcnt(0)\n\ts_barrier" ::: "memory");
}

// ---------------- packed (neuron0, neuron1) Izhikevich ----------------
struct IzhState2 {
    v2f  vnp;   // pre-reset v of previous step, per neuron
    v2f  up;    // u after previous step, per neuron
    bool sx;    // spike of previous step, neuron 0
    bool sy;    // spike of previous step, neuron 1
};

// Select-late step (R5-validated form), packed per-component. Mul/add lower to
// v_pk_*; only the 2 selects + 2 compares + 2 d8-selects are per-component.
// Returns spike as float {0,1} pair (d8*0.125 is exact: {0,8}->{0,1}).
__device__ __forceinline__ v2f izh_step2(IzhState2& s, v2f I) {
#pragma clang fp contract(off)
    const float K0 = ((0.04f * (-65.0f)) * (-65.0f) + (5.0f * (-65.0f))) + 140.0f;
    v2f m2a = 0.04f * s.vnp;
    v2f m2  = m2a * s.vnp;
    v2f f5  = 5.0f * s.vnp;
    v2f s2A = (m2 + f5) + 140.0f;
    v2f s3A = s2A - s.up;
    v2f s4A = s3A + I;
    v2f vnA = s.vnp + s4A;          // no-spike continuation
    v2f s3S = K0 - s.up;
    v2f s4S = s3S + I;
    v2f vnS = (-65.0f) + s4S;       // post-spike continuation (K0 folds exactly)
    v2f vn;
    vn.x = s.sx ? vnS.x : vnA.x;    // the only on-chain selects
    vn.y = s.sy ? vnS.y : vnA.y;
    bool nx = vn.x >= 30.0f;
    bool ny = vn.y >= 30.0f;
    v2f m4 = 0.2f * vn;             // u update, reference op order
    v2f s5 = m4 - s.up;
    v2f tt = 0.02f * s5;
    v2f un = s.up + tt;
    v2f d8;
    d8.x = nx ? 8.0f : 0.0f;
    d8.y = ny ? 8.0f : 0.0f;
    s.up  = un + d8;
    s.vnp = vn;
    s.sx  = nx;
    s.sy  = ny;
    return d8 * 0.125f;             // exact {0,1} spikes, saves 2 cndmask
}

// ---------------- scalar step for the output neuron (unchanged, R5) ----------------
struct IzhState {
    float vnp;
    float up;
    bool  spp;
};

__device__ __forceinline__ bool izh_step(IzhState& s, float I) {
#pragma clang fp contract(off)
    const float K0 = ((0.04f * (-65.0f)) * (-65.0f) + (5.0f * (-65.0f))) + 140.0f;
    float m2a = 0.04f * s.vnp;
    float m2  = m2a * s.vnp;
    float f5  = 5.0f * s.vnp;
    float s2A = (m2 + f5) + 140.0f;
    float s3A = s2A - s.up;
    float s4A = s3A + I;
    float vnA = s.vnp + s4A;
    float s3S = K0 - s.up;
    float s4S = s3S + I;
    float vnS = (-65.0f) + s4S;
    float vn  = s.spp ? vnS : vnA;
    bool  sp  = (vn >= 30.0f);
    float m4  = 0.2f * vn;
    float s5  = m4 - s.up;
    float tt  = 0.02f * s5;
    float un  = s.up + tt;
    float d8  = sp ? 8.0f : 0.0f;
    s.up  = un + d8;
    s.vnp = vn;
    s.spp = sp;
    return sp;
}

// 2-wave block:
//  wid 0: BOTH hidden neurons, packed as v2f per lane (one x load stream)
//  wid 1: output recurrence, lags one round, stores result
__global__ __launch_bounds__(128, 1) void izh2w(
    const float* __restrict__ xs,
    const float* __restrict__ W_in, const float* __restrict__ b_in,
    const float* __restrict__ W_out, const float* __restrict__ b_out,
    float* __restrict__ out)
{
    __shared__ v2f zbuf[2][C][64];   // 32 KB: [parity][step][lane] -> (z0,z1)
    const int lane = threadIdx.x & 63;
    const int wid  = threadIdx.x >> 6;
    const int b    = blockIdx.x * 64 + lane;

    if (wid == 0) {
        // ---------------- packed hidden producer ----------------
#pragma clang fp contract(off)
        // component0 = neuron0, component1 = neuron1
        const v2f wa = { W_in[0], W_in[4] };
        const v2f wb = { W_in[1], W_in[5] };
        const v2f wc = { W_in[2], W_in[6] };
        const v2f wd = { W_in[3], W_in[7] };
        const v2f bi = { b_in[0], b_in[1] };
        const float4* xp = reinterpret_cast<const float4*>(xs) + b;

        // Depth-32 register ring (one full round ahead), refill at consume.
        float4 ring[RD];
#pragma unroll
        for (int i = 0; i < RD; ++i) ring[i] = xp[(size_t)i * B];

        IzhState2 st;
        st.vnp = (v2f){-65.0f, -65.0f};
        st.up  = (v2f){-13.0f, -13.0f};
        st.sx = true; st.sy = true;      // reproduces t=0 exactly (both paths equal)

        for (int r = 0; r < NCH; ++r) {
            const int p = r & 1;
#pragma unroll
            for (int j = 0; j < C; ++j) {
                const int t = r * C + j;
                const float4 x = ring[j & (RD - 1)];
                // refill RD steps ahead; wrap at end (harmless, avoids branch)
                ring[j & (RD - 1)] = xp[(size_t)((t + RD) & (T - 1)) * B];
                // reference op order per component: (((x0*w0)+(x1*w1))+(x2*w2))+(x3*w3) + b
                v2f h = (((x.x * wa) + (x.y * wb)) + (x.z * wc)) + (x.w * wd);
                h = h + bi;
                zbuf[p][j][lane] = izh_step2(st, h);
            }
            barrier_nodrain();
        }
    } else {
        // ---------------- output recurrence (lags 1 round) ----------------
#pragma clang fp contract(off)
        const float wo0 = W_out[0], wo1 = W_out[1], bo = b_out[0];
        // y for z in {0,1}^2 in reference op order -> 4 bit-identical constants
        const float c00 = ((0.0f * wo0) + (0.0f * wo1)) + bo;
        const float c10 = ((1.0f * wo0) + (0.0f * wo1)) + bo;
        const float c01 = ((0.0f * wo0) + (1.0f * wo1)) + bo;
        const float c11 = ((1.0f * wo0) + (1.0f * wo1)) + bo;
        float* op = out + b;
        IzhState st{-65.0f, -13.0f, true};

        auto consume = [&](int kk) {
#pragma clang fp contract(off)
            const int p = kk & 1;
            v2f z[C];
#pragma unroll
            for (int j = 0; j < C; ++j) z[j] = zbuf[p][j][lane];   // ds_read_b64
#pragma unroll
            for (int j = 0; j < C; ++j) {
                float yt = (z[j].y != 0.0f) ? c11 : c10;
                float yf = (z[j].y != 0.0f) ? c01 : c00;
                float y  = (z[j].x != 0.0f) ? yt : yf;
                bool spo = izh_step(st, y);
                op[(size_t)(kk * C + j) * B] = spo ? 1.0f : 0.0f;
            }
        };

        for (int r = 0; r < NCH; ++r) {
            if (r > 0) consume(r - 1);   // wave-uniform branch
            barrier_nodrain();
        }
        consume(NCH - 1);                // epilogue: last round, no barrier
    }
}

} // namespace

extern "C" void kernel_launch(void* const* d_in, const int* in_sizes, int n_in,
                              void* d_out, int out_size, void* d_ws, size_t ws_size,
                              hipStream_t stream) {
    const float* xs    = (const float*)d_in[0];
    const float* W_in  = (const float*)d_in[1];
    const float* b_in  = (const float*)d_in[2];
    const float* W_out = (const float*)d_in[3];
    const float* b_out = (const float*)d_in[4];
    float* out = (float*)d_out;

    dim3 grid(B / 64), block(128);   // 128 blocks x 2 waves
    hipLaunchKernelGGL(izh2w, grid, block, 0, stream,
                       xs, W_in, b_in, W_out, b_out, out);
}

// Round 2
// 480.295 us; speedup vs baseline: 1.0621x; 1.0621x over previous
//
#include <hip/hip_runtime.h>

namespace {

constexpr int T   = 2048;
constexpr int B   = 8192;
constexpr int C   = 32;        // steps per pipeline round
constexpr int NCH = T / C;     // 64 data rounds
constexpr int RD  = 32;        // x prefetch ring depth (one full round)

// LDS-only barrier: waits lgkmcnt(0), leaves vmcnt alone so global prefetch
// stays in flight across rounds (R4-proven).
__device__ __forceinline__ void barrier_nodrain() {
    asm volatile("s_waitcnt lgkmcnt(0)\n\ts_barrier" ::: "memory");
}

struct IzhState {
    float vnp;   // v of previous step (pre-reset value)
    float up;    // u after previous step
    bool  spp;   // spike of previous step
};

// Select-EARLY Izhikevich step. Bit-exact vs the R5-validated select-late form:
// each path evaluates the identical op sequence on identical values
//   !spp: vn = vnp + (((0.04*vnp*vnp + 5*vnp + 140) - up) + I)
//    spp: vn = -65  + ((K0 - up) + I)          (K0 folds at compile time)
// but the selection happens on the inputs (2 cndmask) instead of 2 adds + 1
// cndmask on the outputs -> 17 VALU ops instead of 19.
// Returns d8 = spike*8.0f (the value the u-update already needs), so callers
// get the spike for free; z = d8*0.125f is exact ({0,8}->{0,1}, +0 sign kept).
__device__ __forceinline__ float izh_step(IzhState& s, float I) {
#pragma clang fp contract(off)
    const float K0 = ((0.04f * (-65.0f)) * (-65.0f) + (5.0f * (-65.0f))) + 140.0f;
    float m2a = 0.04f * s.vnp;
    float m2  = m2a * s.vnp;
    float f5  = 5.0f * s.vnp;
    float s2A = (m2 + f5) + 140.0f;
    float pre = s.spp ? K0 : s2A;        // select-early: quadratic term
    float bse = s.spp ? -65.0f : s.vnp;  // select-early: base v
    float s3  = pre - s.up;
    float s4  = s3 + I;
    float vn  = bse + s4;
    bool  sp  = (vn >= 30.0f);
    float m4  = 0.2f * vn;               // u update, reference op order
    float s5  = m4 - s.up;
    float tt  = 0.02f * s5;
    float un  = s.up + tt;
    float d8  = sp ? 8.0f : 0.0f;
    s.up  = un + d8;
    s.vnp = vn;
    s.spp = sp;
    return d8;
}

// 6-wave pipelined block, 64 batch lanes, 32-step rounds.
// Round rr activities (all guards wave-uniform; parity = chunk&1):
//   waves 4,5 (h):      produce hbuf[chunk rr+1]          (prologue: chunk 0)
//   waves 0,1 (hidden): consume hbuf[rr]   -> dbuf[rr]    (izh recurrence)
//   wave 3   (y+store): consume dbuf[rr-1] -> ybuf[rr-1]; obuf[rr-3] -> global
//   wave 2   (output):  consume ybuf[rr-2] -> obuf[rr-2]  (izh recurrence)
// Each buffer is written in round r and read in round r+1; next write of the
// same parity is round r+2 -> double-buffer safe under one barrier per round.
__global__ __launch_bounds__(384, 1) void izh6w(
    const float* __restrict__ xs,
    const float* __restrict__ W_in, const float* __restrict__ b_in,
    const float* __restrict__ W_out, const float* __restrict__ b_out,
    float* __restrict__ out)
{
    // All tiles grouped by 4 steps so every LDS access is ds_read/write_b128
    // at lane*16 (conflict-free). Component [j&3] is compile-time after unroll.
    __shared__ float4 hbuf[2][2][8][64];  // [neuron][parity][j>>2][lane] : h
    __shared__ float4 dbuf[2][2][8][64];  // [neuron][parity][j>>2][lane] : d8 spikes
    __shared__ float4 ybuf[2][8][64];     // [parity][j>>2][lane]         : y
    __shared__ float4 obuf[2][8][64];     // [parity][j>>2][lane]         : out spikes
    const int lane = threadIdx.x & 63;
    const int wid  = threadIdx.x >> 6;
    const int b    = blockIdx.x * 64 + lane;

    if (wid >= 4) {
        // ---------------- h producer for neuron n (slack wave) ----------------
#pragma clang fp contract(off)
        const int n = wid - 4;
        const float wa = W_in[n * 4 + 0], wb = W_in[n * 4 + 1];
        const float wc = W_in[n * 4 + 2], wd = W_in[n * 4 + 3];
        const float bi = b_in[n];
        const float4* xp = reinterpret_cast<const float4*>(xs) + b;

        float4 ring[RD];
#pragma unroll
        for (int i = 0; i < RD; ++i) ring[i] = xp[(size_t)i * B];

        // prologue: chunk 0 into parity 0
        {
            float4 hr[8];
#pragma unroll
            for (int j = 0; j < C; ++j) {
                const float4 x = ring[j];
                ring[j] = xp[(size_t)((j + RD) & (T - 1)) * B];
                float h = ((((x.x * wa) + (x.y * wb)) + (x.z * wc)) + (x.w * wd)) + bi;
                reinterpret_cast<float*>(&hr[j >> 2])[j & 3] = h;
            }
#pragma unroll
            for (int q = 0; q < 8; ++q) hbuf[n][0][q][lane] = hr[q];
        }
        barrier_nodrain();

        for (int rr = 0; rr < NCH + 3; ++rr) {
            if (rr + 1 < NCH) {
                const int c = rr + 1, p = c & 1;
                float4 hr[8];
#pragma unroll
                for (int j = 0; j < C; ++j) {
                    const int t = c * C + j;
                    const float4 x = ring[j];
                    ring[j] = xp[(size_t)((t + RD) & (T - 1)) * B];
                    float h = ((((x.x * wa) + (x.y * wb)) + (x.z * wc)) + (x.w * wd)) + bi;
                    reinterpret_cast<float*>(&hr[j >> 2])[j & 3] = h;
                }
#pragma unroll
                for (int q = 0; q < 8; ++q) hbuf[n][p][q][lane] = hr[q];
            }
            barrier_nodrain();
        }
    } else if (wid < 2) {
        // ---------------- hidden izh recurrence, neuron n (critical) ----------------
#pragma clang fp contract(off)
        const int n = wid;
        IzhState st{-65.0f, -13.0f, true};
        barrier_nodrain();
        for (int rr = 0; rr < NCH + 3; ++rr) {
            if (rr < NCH) {
                const int p = rr & 1;
                float4 hr[8];
#pragma unroll
                for (int q = 0; q < 8; ++q) hr[q] = hbuf[n][p][q][lane];
                float4 dr[8];
#pragma unroll
                for (int j = 0; j < C; ++j) {
                    float h  = reinterpret_cast<const float*>(&hr[j >> 2])[j & 3];
                    float d8 = izh_step(st, h);
                    reinterpret_cast<float*>(&dr[j >> 2])[j & 3] = d8;
                }
#pragma unroll
                for (int q = 0; q < 8; ++q) dbuf[n][p][q][lane] = dr[q];
            }
            barrier_nodrain();
        }
    } else if (wid == 2) {
        // ---------------- output izh recurrence (critical) ----------------
#pragma clang fp contract(off)
        IzhState st{-65.0f, -13.0f, true};
        barrier_nodrain();
        for (int rr = 0; rr < NCH + 3; ++rr) {
            if (rr >= 2 && rr <= NCH + 1) {
                const int c = rr - 2, p = c & 1;
                float4 yr[8];
#pragma unroll
                for (int q = 0; q < 8; ++q) yr[q] = ybuf[p][q][lane];
                float4 orr[8];
#pragma unroll
                for (int j = 0; j < C; ++j) {
                    float y  = reinterpret_cast<const float*>(&yr[j >> 2])[j & 3];
                    float d8 = izh_step(st, y);
                    // exact {0,8} -> {0,1}
                    reinterpret_cast<float*>(&orr[j >> 2])[j & 3] = d8 * 0.125f;
                }
#pragma unroll
                for (int q = 0; q < 8; ++q) obuf[p][q][lane] = orr[q];
            }
            barrier_nodrain();
        }
    } else {
        // ---------------- y-combine + global store service (slack wave) ----------------
#pragma clang fp contract(off)
        const float wo0 = W_out[0], wo1 = W_out[1], bo = b_out[0];
        float* op = out + b;
        barrier_nodrain();
        for (int rr = 0; rr < NCH + 3; ++rr) {
            // y for chunk rr-1: z = d8*0.125 (exact), then reference op order
            // ((z0*wo0)+(z1*wo1))+bo — all products exact, bit-identical.
            if (rr >= 1 && rr <= NCH) {
                const int c = rr - 1, p = c & 1;
                float4 a0r[8], a1r[8];
#pragma unroll
                for (int q = 0; q < 8; ++q) a0r[q] = dbuf[0][p][q][lane];
#pragma unroll
                for (int q = 0; q < 8; ++q) a1r[q] = dbuf[1][p][q][lane];
                float4 yr[8];
#pragma unroll
                for (int j = 0; j < C; ++j) {
                    float z0 = reinterpret_cast<const float*>(&a0r[j >> 2])[j & 3] * 0.125f;
                    float z1 = reinterpret_cast<const float*>(&a1r[j >> 2])[j & 3] * 0.125f;
                    float y  = ((z0 * wo0) + (z1 * wo1)) + bo;
                    reinterpret_cast<float*>(&yr[j >> 2])[j & 3] = y;
                }
#pragma unroll
                for (int q = 0; q < 8; ++q) ybuf[p][q][lane] = yr[q];
            }
            // drain output spikes of chunk rr-3 to global
            if (rr >= 3) {
                const int c = rr - 3, p = c & 1;
                float4 orr[8];
#pragma unroll
                for (int q = 0; q < 8; ++q) orr[q] = obuf[p][q][lane];
#pragma unroll
                for (int j = 0; j < C; ++j) {
                    op[(size_t)(c * C + j) * B] =
                        reinterpret_cast<const float*>(&orr[j >> 2])[j & 3];
                }
            }
            barrier_nodrain();
        }
    }
}

} // namespace

extern "C" void kernel_launch(void* const* d_in, const int* in_sizes, int n_in,
                              void* d_out, int out_size, void* d_ws, size_t ws_size,
                              hipStream_t stream) {
    const float* xs    = (const float*)d_in[0];
    const float* W_in  = (const float*)d_in[1];
    const float* b_in  = (const float*)d_in[2];
    const float* W_out = (const float*)d_in[3];
    const float* b_out = (const float*)d_in[4];
    float* out = (float*)d_out;

    dim3 grid(B / 64), block(384);   // 128 blocks x 6 waves
    hipLaunchKernelGGL(izh6w, grid, block, 0, stream,
                       xs, W_in, b_in, W_out, b_out, out);
}